// Round 5
// baseline (9579.762 us; speedup 1.0000x reference)
//
#include <hip/hip_runtime.h>
#include <cstdint>

typedef _Float16 f16;
typedef _Float16 f16x8 __attribute__((ext_vector_type(8)));
typedef float    f32x4 __attribute__((ext_vector_type(4)));

#define DINL __device__ __forceinline__

static constexpr int HID = 1024;
static constexpr int NG  = 4096;   // 4*HID gate count
static constexpr int BB  = 256;    // batch
static constexpr int TT  = 100;    // seq len
static constexpr int KX  = 256;    // padded input-feature K (227 -> 256)
static constexpr size_t MSZ = (size_t)NG * HID;   // halves per packed [4096][1024] mat

// ---- workspace layout (bytes). total ~119 MiB ----
static constexpr size_t OFF_PACKW5 = 0;
static constexpr size_t OFF_W1D    = OFF_PACKW5 + 5*MSZ*2;
static constexpr size_t OFF_WIH1   = OFF_W1D   + MSZ*2;
static constexpr size_t OFF_WD     = OFF_WIH1  + (size_t)NG*KX*2;
static constexpr size_t OFF_XPAD   = OFF_WD    + (size_t)256*HID*2;
static constexpr size_t OFF_BIAS   = OFF_XPAD  + (size_t)TT*BB*KX*2;
static constexpr size_t OFF_C      = OFF_BIAS  + (size_t)4*NG*4;
static constexpr size_t OFF_HBUF   = OFF_C     + (size_t)3*BB*HID*4;
static constexpr size_t OFF_H2Z    = OFF_HBUF  + (size_t)4*BB*HID*2;
static constexpr size_t OFF_H2ALL  = OFF_H2Z   + (size_t)BB*HID*2;
// WdT scratch ([1024][256] f16) lives at OFF_H2ALL until k_w1d consumes it.

DINL void async16(void* lds, const void* g){
  auto lp = reinterpret_cast<__attribute__((address_space(3))) unsigned int*>(
      reinterpret_cast<uintptr_t>(lds));
  auto gp = reinterpret_cast<const __attribute__((address_space(1))) unsigned int*>(
      reinterpret_cast<uintptr_t>(g));
  __builtin_amdgcn_global_load_lds(gp, lp, 16, 0, 0);
}

DINL float sigf(float x){
  x = fminf(fmaxf(x, -30.f), 30.f);
  return __fdividef(1.f, 1.f + __expf(-x));
}
DINL float tanh_fast(float x){
  x = fminf(fmaxf(x, -15.f), 15.f);
  float t = __expf(2.f*x);
  return __fdividef(t - 1.f, t + 1.f);
}

// ---- single-buffered 128x128 tile core (k_w1d / k_final only) ----
DINL void gemm_tile(f32x4 acc[4][4],
                    const f16* __restrict__ A, int m0, int sA,
                    const f16* __restrict__ Bp, int n0, int K,
                    char* ldsA, char* ldsB, int w, int lane)
{
  const int m_w = (w>>1)*64, n_w = (w&1)*64, c15 = lane&15;
  for (int k0 = 0; k0 < K; k0 += 64){
    __syncthreads();
    #pragma unroll
    for (int q = 0; q < 4; q++){
      int r0  = w*32 + q*8;
      int row = r0 + (lane>>3);
      int kg  = (lane&7) ^ (row&7);
      async16(ldsA + r0*128, A  + (size_t)(m0+row)*sA + k0 + kg*8);
      async16(ldsB + r0*128, Bp + (size_t)(n0+row)*K  + k0 + kg*8);
    }
    __syncthreads();
    #pragma unroll
    for (int kw = 0; kw < 2; kw++){
      f16x8 af[4], bf[4];
      #pragma unroll
      for (int ti = 0; ti < 4; ti++){
        int row  = m_w + ti*16 + c15;
        int phys = (kw*4 + (lane>>4)) ^ (row&7);
        af[ti] = *(const f16x8*)(ldsA + row*128 + phys*16);
      }
      #pragma unroll
      for (int tj = 0; tj < 4; tj++){
        int row  = n_w + tj*16 + c15;
        int phys = (kw*4 + (lane>>4)) ^ (row&7);
        bf[tj] = *(const f16x8*)(ldsB + row*128 + phys*16);
      }
      #pragma unroll
      for (int ti = 0; ti < 4; ti++)
        #pragma unroll
        for (int tj = 0; tj < 4; tj++)
          acc[ti][tj] = __builtin_amdgcn_mfma_f32_16x16x32_f16(af[ti], bf[tj], acc[ti][tj], 0, 0, 0);
    }
  }
}

// ================= prep kernels =================

__global__ void k_pack5(const float* W0, const float* W1, const float* W2,
                        const float* W3, const float* W4, char* ws)
{
  f16* dst = (f16*)(ws + OFF_PACKW5);
  const int mat = blockIdx.y;
  const float* src = mat==0?W0 : mat==1?W1 : mat==2?W2 : mat==3?W3 : W4;
  int tid = blockIdx.x*256 + threadIdx.x;
  int n = tid >> 7, kc = tid & 127;
  int r = ((n&3) << 10) + (n >> 2);
  const float* s = src + (size_t)r*HID + kc*8;
  f16x8 o;
  #pragma unroll
  for (int i = 0; i < 8; i++) o[i] = (f16)s[i];
  *(f16x8*)(dst + (size_t)mat*MSZ + (size_t)n*HID + kc*8) = o;
}

__global__ void k_packwih1(const float* __restrict__ Wih1, char* ws){
  f16* dst = (f16*)(ws + OFF_WIH1);
  int n = blockIdx.x, k = threadIdx.x;
  int r = ((n&3) << 10) + (n >> 2);
  dst[(size_t)n*KX + k] = (k < 227) ? (f16)Wih1[(size_t)r*227 + k] : (f16)0.f;
}

__global__ void k_packwd(const float* __restrict__ Wd, char* ws){
  f16* dst = (f16*)(ws + OFF_WD);
  int o = blockIdx.x;
  #pragma unroll
  for (int j = 0; j < 4; j++){
    int k = threadIdx.x + j*256;
    dst[(size_t)o*HID + k] = (o < 227) ? (f16)Wd[(size_t)o*HID + k] : (f16)0.f;
  }
}

__global__ void k_packwdt(const float* __restrict__ Wd, char* ws){
  f16* dst = (f16*)(ws + OFF_H2ALL);
  int h = blockIdx.x, o = threadIdx.x;
  dst[(size_t)h*KX + o] = (o < 227) ? (f16)Wd[(size_t)o*HID + h] : (f16)0.f;
}

__global__ void k_xpad(const float* __restrict__ seq, char* ws){
  f16* dst = (f16*)(ws + OFF_XPAD);
  int idx = blockIdx.x*256 + threadIdx.x;
  int t = idx >> 16, rem = idx & 65535, b = rem >> 8, k = rem & 255;
  dst[idx] = (k < 227) ? (f16)seq[(size_t)b*22700 + (size_t)t*227 + k] : (f16)0.f;
}

__global__ void k_bias(const float* bih1, const float* bhh1, const float* bih2, const float* bhh2,
                       const float* bih3, const float* bhh3, const float* Wih1, const float* bd,
                       char* ws)
{
  int n = blockIdx.x*256 + threadIdx.x;
  if (n >= NG) return;
  int r = ((n&3) << 10) + (n >> 2);
  float* b = (float*)(ws + OFF_BIAS);
  float bf = bih1[r] + bhh1[r];
  float s = 0.f;
  for (int o = 0; o < 227; o++) s += Wih1[(size_t)r*227 + o] * bd[o];
  b[n]        = bf;
  b[NG + n]   = bf + s;
  b[2*NG + n] = bih2[r] + bhh2[r];
  b[3*NG + n] = bih3[r] + bhh3[r];
}

__global__ __launch_bounds__(256, 2) void k_w1d(char* ws)
{
  __shared__ __align__(16) char ldsA[16384];
  __shared__ __align__(16) char ldsB[16384];
  const int w = threadIdx.x >> 6, lane = threadIdx.x & 63;
  const int n0 = blockIdx.x*128, m0 = blockIdx.y*128;
  const f16* A  = (const f16*)(ws + OFF_WIH1);
  const f16* Bp = (const f16*)(ws + OFF_H2ALL);
  f16* W1D = (f16*)(ws + OFF_W1D);

  f32x4 acc[4][4];
  f32x4 zero = {0.f, 0.f, 0.f, 0.f};
  #pragma unroll
  for (int i = 0; i < 4; i++)
    #pragma unroll
    for (int j = 0; j < 4; j++) acc[i][j] = zero;

  gemm_tile(acc, A, m0, KX, Bp, n0, KX, ldsA, ldsB, w, lane);

  const int m_w = (w>>1)*64, n_w = (w&1)*64, quad = lane>>4, c15 = lane&15;
  #pragma unroll
  for (int tj = 0; tj < 4; tj++){
    int col = n0 + n_w + tj*16 + c15;
    #pragma unroll
    for (int ti = 0; ti < 4; ti++){
      f32x4 v = acc[ti][tj];
      #pragma unroll
      for (int r = 0; r < 4; r++){
        int m = m0 + m_w + ti*16 + quad*4 + r;
        W1D[(size_t)m*HID + col] = (f16)v[r];
      }
    }
  }
}

// ================= recurrent step kernel: LDS-free, direct-to-VGPR fragments =================
// grid (64 ntiles, 3 layers, 2 mtiles) = 384 blocks, 256 threads, tile 128m x 64n.
// 4 waves in 2x2; each wave computes 64m x 32n. MFMA fragments are loaded DIRECTLY
// from global with per-lane global_load_dwordx4 (frag layout A[c15][kw*32+quad*8+j] is
// 16B contiguous per lane). No LDS, no LDS-DMA (shallow HW queue made it ~latency-
// serialized), no barriers. Depth-3 register staging: loads for chunk c+3 issued while
// computing chunk c -> >=2 chunk-periods of latency slack per wave; compiler inserts
// precise vmcnt waits for plain loads.
__global__ __launch_bounds__(256, 2) void k_step(char* __restrict__ ws, int t, int use_gt)
{
  const int w = threadIdx.x >> 6, lane = threadIdx.x & 63;
  const int wm = w >> 1, wn = w & 1;
  const int col0 = blockIdx.x*64, layer = blockIdx.y, m0 = blockIdx.z*128;
  const int c15 = lane & 15, quad = lane >> 4;

  const f16* packW = (const f16*)(ws + OFF_PACKW5);
  const f16* W1D   = (const f16*)(ws + OFF_W1D);
  const f16* WIH1  = (const f16*)(ws + OFF_WIH1);
  const f16* XP    = (const f16*)(ws + OFF_XPAD) + (size_t)t*BB*KX;
  const float* biasb = (const float*)(ws + OFF_BIAS);
  float* Cst = (float*)(ws + OFF_C);
  f16* HB  = (f16*)(ws + OFF_HBUF);
  f16* H2Z = (f16*)(ws + OFF_H2Z);
  f16* H2A = (f16*)(ws + OFF_H2ALL);

  const int pr = t & 1, pw = pr ^ 1;
  const f16* h0p = HB + (size_t)(pr*2 + 0)*BB*HID;
  const f16* h1p = HB + (size_t)(pr*2 + 1)*BB*HID;
  const f16* h2p = (t == 0) ? H2Z : (H2A + (size_t)(t-1)*BB*HID);

  const f16 *A0, *A1, *B0, *B1; int K1, sA1;
  const float* biasp; f16* hout; float* cptr;
  if (layer == 0){
    A0 = h0p; B0 = packW;
    if (use_gt){ A1 = XP;  B1 = WIH1; K1 = KX;  sA1 = KX;  biasp = biasb; }
    else       { A1 = h2p; B1 = W1D;  K1 = HID; sA1 = HID; biasp = biasb + NG; }
    hout = HB + (size_t)(pw*2 + 0)*BB*HID; cptr = Cst;
  } else if (layer == 1){
    A0 = h0p; B0 = packW + MSZ;  A1 = h1p; B1 = packW + 2*MSZ; K1 = HID; sA1 = HID;
    biasp = biasb + 2*NG; hout = HB + (size_t)(pw*2 + 1)*BB*HID; cptr = Cst + (size_t)BB*HID;
  } else {
    A0 = h1p; B0 = packW + 3*MSZ; A1 = h2p; B1 = packW + 4*MSZ; K1 = HID; sA1 = HID;
    biasp = biasb + 3*NG; hout = H2A + (size_t)t*BB*HID; cptr = Cst + (size_t)2*BB*HID;
  }
  const int ncmax = 16 + (K1 >> 6);   // 32, or 20 (teacher-forced layer 0)

  // per-lane fragment base pointers; chunk c adds (c<16? c : c-16)*64 elements
  const int arow = m0 + wm*64 + c15;
  const int brow = col0 + wn*32 + c15;
  const f16* a0b[4]; const f16* a1b[4];
  #pragma unroll
  for (int ti = 0; ti < 4; ti++){
    a0b[ti] = A0 + (size_t)(arow + ti*16)*HID + quad*8;
    a1b[ti] = A1 + (size_t)(arow + ti*16)*sA1 + quad*8;
  }
  const f16* b0b[2]; const f16* b1b[2];
  #pragma unroll
  for (int tj = 0; tj < 2; tj++){
    b0b[tj] = B0 + (size_t)(brow + tj*16)*HID + quad*8;
    b1b[tj] = B1 + (size_t)(brow + tj*16)*K1 + quad*8;
  }

  f16x8 sA[3][4][2];   // [stage][ti][kw]
  f16x8 sB[3][2][2];   // [stage][tj][kw]
  f32x4 acc[4][2];
  f32x4 zero = {0.f, 0.f, 0.f, 0.f};
  #pragma unroll
  for (int i = 0; i < 4; i++)
    #pragma unroll
    for (int j = 0; j < 2; j++) acc[i][j] = zero;

#define LDC(cv, st) { const int cc_ = (cv); const int off_ = ((cc_ < 16) ? cc_ : cc_ - 16)*64;   \
  _Pragma("unroll") for (int ti_ = 0; ti_ < 4; ti_++){                                           \
    const f16* p_ = (cc_ < 16) ? a0b[ti_] : a1b[ti_];                                            \
    sA[st][ti_][0] = *(const f16x8*)(p_ + off_);                                                 \
    sA[st][ti_][1] = *(const f16x8*)(p_ + off_ + 32); }                                          \
  _Pragma("unroll") for (int tj_ = 0; tj_ < 2; tj_++){                                           \
    const f16* p_ = (cc_ < 16) ? b0b[tj_] : b1b[tj_];                                            \
    sB[st][tj_][0] = *(const f16x8*)(p_ + off_);                                                 \
    sB[st][tj_][1] = *(const f16x8*)(p_ + off_ + 32); } }

#define CMP(st) {                                                                                \
  _Pragma("unroll") for (int kw_ = 0; kw_ < 2; kw_++)                                            \
  _Pragma("unroll") for (int ti_ = 0; ti_ < 4; ti_++)                                            \
  _Pragma("unroll") for (int tj_ = 0; tj_ < 2; tj_++)                                            \
    acc[ti_][tj_] = __builtin_amdgcn_mfma_f32_16x16x32_f16(sA[st][ti_][kw_], sB[st][tj_][kw_],   \
                                                           acc[ti_][tj_], 0, 0, 0); }

  LDC(0, 0); LDC(1, 1); LDC(2, 2);
  for (int cc = 0; cc < ncmax; cc += 3){
    CMP(0); if (cc + 3 < ncmax) LDC(cc + 3, 0);
    if (cc + 1 < ncmax){ CMP(1); if (cc + 4 < ncmax) LDC(cc + 4, 1); }
    if (cc + 2 < ncmax){ CMP(2); if (cc + 5 < ncmax) LDC(cc + 5, 2); }
  }
#undef LDC
#undef CMP

  // ---- fused LSTM cell epilogue (per-lane single activation, shuffle after) ----
  const int gl = lane & 3, sbase = lane & 60;
  const int mb = m0 + wm*64;
  #pragma unroll
  for (int tj = 0; tj < 2; tj++){
    const int ncol = col0 + wn*32 + tj*16 + c15;
    const int unit = ncol >> 2;
    const float bn = biasp[ncol];
    float cp[16];
    #pragma unroll
    for (int ti = 0; ti < 4; ti++)
      #pragma unroll
      for (int r = 0; r < 4; r++)
        cp[ti*4 + r] = cptr[(size_t)(mb + ti*16 + quad*4 + r)*HID + unit];
    #pragma unroll
    for (int ti = 0; ti < 4; ti++){
      f32x4 v = acc[ti][tj];
      #pragma unroll
      for (int r = 0; r < 4; r++){
        float x   = v[r] + bn;
        float act = (gl == 2) ? tanh_fast(x) : sigf(x);   // lane's own gate only
        float iv = __shfl(act, sbase);
        float fv = __shfl(act, sbase + 1);
        float gv = __shfl(act, sbase + 2);
        float ov = __shfl(act, sbase + 3);
        float cn = fmaf(fv, cp[ti*4 + r], iv*gv);
        float hn = ov * tanh_fast(cn);
        int m = mb + ti*16 + quad*4 + r;
        if (gl == 0)      cptr[(size_t)m*HID + unit] = cn;
        else if (gl == 1) hout[(size_t)m*HID + unit] = (f16)hn;
      }
    }
  }
}

// ================= final output GEMM =================
__global__ __launch_bounds__(256, 2) void k_final(const char* __restrict__ ws,
                                                  const float* __restrict__ bd,
                                                  float* __restrict__ dout)
{
  __shared__ __align__(16) char ldsA[16384];
  __shared__ __align__(16) char ldsB[16384];
  const int w = threadIdx.x >> 6, lane = threadIdx.x & 63;
  const int n0 = blockIdx.x*128, m0 = blockIdx.y*128;
  const f16* A  = (const f16*)(ws + OFF_H2ALL);
  const f16* Bp = (const f16*)(ws + OFF_WD);

  f32x4 acc[4][4];
  f32x4 zero = {0.f, 0.f, 0.f, 0.f};
  #pragma unroll
  for (int i = 0; i < 4; i++)
    #pragma unroll
    for (int j = 0; j < 4; j++) acc[i][j] = zero;

  gemm_tile(acc, A, m0, HID, Bp, n0, HID, ldsA, ldsB, w, lane);

  const int m_w = (w>>1)*64, n_w = (w&1)*64, quad = lane>>4, c15 = lane&15;
  #pragma unroll
  for (int tj = 0; tj < 4; tj++){
    int o = n0 + n_w + tj*16 + c15;
    bool valid = (o < 227);
    float bn = valid ? bd[o] : 0.f;
    #pragma unroll
    for (int ti = 0; ti < 4; ti++){
      f32x4 v = acc[ti][tj];
      #pragma unroll
      for (int r = 0; r < 4; r++){
        int m = m0 + m_w + ti*16 + quad*4 + r;
        if (valid){
          int tt = m >> 8, b = m & 255;
          dout[(size_t)b*22700 + (size_t)tt*227 + o] = v[r] + bn;
        }
      }
    }
  }
}

// ================= host =================
extern "C" void kernel_launch(void* const* d_in, const int* in_sizes, int n_in,
                              void* d_out, int out_size, void* d_ws, size_t ws_size,
                              hipStream_t stream)
{
  (void)in_sizes; (void)n_in; (void)out_size; (void)ws_size;
  const float* seq  = (const float*)d_in[0];
  const float* Wih1 = (const float*)d_in[1];
  const float* Whh1 = (const float*)d_in[2];
  const float* bih1 = (const float*)d_in[3];
  const float* bhh1 = (const float*)d_in[4];
  const float* Wih2 = (const float*)d_in[5];
  const float* Whh2 = (const float*)d_in[6];
  const float* bih2 = (const float*)d_in[7];
  const float* bhh2 = (const float*)d_in[8];
  const float* Wih3 = (const float*)d_in[9];
  const float* Whh3 = (const float*)d_in[10];
  const float* bih3 = (const float*)d_in[11];
  const float* bhh3 = (const float*)d_in[12];
  const float* Wd   = (const float*)d_in[13];
  const float* bd   = (const float*)d_in[14];
  char* ws = (char*)d_ws;

  hipMemsetAsync(ws + OFF_C,    0, (size_t)3*BB*HID*4, stream);
  hipMemsetAsync(ws + OFF_HBUF, 0, (size_t)2*BB*HID*2, stream);
  hipMemsetAsync(ws + OFF_H2Z,  0, (size_t)BB*HID*2,   stream);

  k_pack5   <<<dim3(2048, 5), dim3(256), 0, stream>>>(Whh1, Wih2, Whh2, Wih3, Whh3, ws);
  k_packwih1<<<dim3(4096),    dim3(256), 0, stream>>>(Wih1, ws);
  k_packwd  <<<dim3(256),     dim3(256), 0, stream>>>(Wd, ws);
  k_packwdt <<<dim3(1024),    dim3(256), 0, stream>>>(Wd, ws);
  k_xpad    <<<dim3(25600),   dim3(256), 0, stream>>>(seq, ws);
  k_bias    <<<dim3(16),      dim3(256), 0, stream>>>(bih1, bhh1, bih2, bhh2, bih3, bhh3, Wih1, bd, ws);
  k_w1d     <<<dim3(8, 32),   dim3(256), 0, stream>>>(ws);

  for (int t = 0; t < TT; t++){
    int ug = ((t % 10) < 5) ? 1 : 0;
    k_step<<<dim3(64, 3, 2), dim3(256), 0, stream>>>(ws, t, ug);
  }

  k_final<<<dim3(2, 200), dim3(256), 0, stream>>>((const char*)ws, bd, (float*)d_out);
}

// Round 6
// 4341.768 us; speedup vs baseline: 2.2064x; 2.2064x over previous
//
#include <hip/hip_runtime.h>
#include <cstdint>

typedef _Float16 f16;
typedef _Float16 f16x8 __attribute__((ext_vector_type(8)));
typedef float    f32x4 __attribute__((ext_vector_type(4)));

#define DINL __device__ __forceinline__

static constexpr int HID = 1024;
static constexpr int NG  = 4096;   // 4*HID gate count
static constexpr int BB  = 256;    // batch
static constexpr int TT  = 100;    // seq len
static constexpr int KX  = 256;    // padded input-feature K (227 -> 256)
static constexpr size_t MSZ = (size_t)NG * HID;   // halves per packed [4096][1024] mat

// ALL GEMM operands are stored CHUNK-MAJOR: [kc][row][64] (kc = K/64 chunk).
// Chunk strides (elements): weights = NG*64 = 262144; h-state bufs = BB*64 = 16384;
// H2A history = 25600*64 = 1638400; XPAD per-t = 16384; WdT' = 65536; WD' = 16384.

// ---- workspace layout (bytes). total ~119 MiB ----
static constexpr size_t OFF_PACKW5 = 0;
static constexpr size_t OFF_W1D    = OFF_PACKW5 + 5*MSZ*2;
static constexpr size_t OFF_WIH1   = OFF_W1D   + MSZ*2;
static constexpr size_t OFF_WD     = OFF_WIH1  + (size_t)NG*KX*2;
static constexpr size_t OFF_XPAD   = OFF_WD    + (size_t)256*HID*2;
static constexpr size_t OFF_BIAS   = OFF_XPAD  + (size_t)TT*BB*KX*2;
static constexpr size_t OFF_C      = OFF_BIAS  + (size_t)4*NG*4;
static constexpr size_t OFF_HBUF   = OFF_C     + (size_t)3*BB*HID*4;
static constexpr size_t OFF_H2Z    = OFF_HBUF  + (size_t)4*BB*HID*2;
static constexpr size_t OFF_H2ALL  = OFF_H2Z   + (size_t)BB*HID*2;
// WdT' scratch ([4][1024][64] f16) lives at OFF_H2ALL until k_w1d consumes it.

static constexpr size_t CS_W  = 262144;   // weight chunk stride (elements)
static constexpr size_t CS_H  = 16384;    // h-buffer chunk stride
static constexpr size_t CS_H2 = 1638400;  // H2A global chunk stride

DINL void async16(void* lds, const void* g){
  auto lp = reinterpret_cast<__attribute__((address_space(3))) unsigned int*>(
      reinterpret_cast<uintptr_t>(lds));
  auto gp = reinterpret_cast<const __attribute__((address_space(1))) unsigned int*>(
      reinterpret_cast<uintptr_t>(g));
  __builtin_amdgcn_global_load_lds(gp, lp, 16, 0, 0);
}

DINL float sigf(float x){
  x = fminf(fmaxf(x, -30.f), 30.f);
  return __fdividef(1.f, 1.f + __expf(-x));
}
DINL float tanh_fast(float x){
  x = fminf(fmaxf(x, -15.f), 15.f);
  float t = __expf(2.f*x);
  return __fdividef(t - 1.f, t + 1.f);
}

// ---- 128x128 tile core, chunk-major operands (k_w1d / k_final) ----
DINL void gemm_tile_cm(f32x4 acc[4][4],
                       const f16* __restrict__ A, size_t csA, int m0,
                       const f16* __restrict__ B, size_t csB, int n0, int K,
                       char* ldsA, char* ldsB, int w, int lane)
{
  const int m_w = (w>>1)*64, n_w = (w&1)*64, c15 = lane&15;
  const int lr = lane>>3, lb = lane&7;
  const int sw8 = (lb ^ lr) * 8;                 // source-side XOR swizzle (DMA dest is lane-linear)
  for (int k0 = 0; k0 < K; k0 += 64){
    const size_t kc = (size_t)(k0 >> 6);
    __syncthreads();
    #pragma unroll
    for (int q = 0; q < 4; q++){
      int r0 = w*32 + q*8;
      async16(ldsA + r0*128, A + kc*csA + (size_t)(m0 + r0 + lr)*64 + sw8);
      async16(ldsB + r0*128, B + kc*csB + (size_t)(n0 + r0 + lr)*64 + sw8);
    }
    __syncthreads();
    #pragma unroll
    for (int kw = 0; kw < 2; kw++){
      f16x8 af[4], bf[4];
      #pragma unroll
      for (int ti = 0; ti < 4; ti++){
        int row  = m_w + ti*16 + c15;
        int phys = (kw*4 + (lane>>4)) ^ (row&7);
        af[ti] = *(const f16x8*)(ldsA + row*128 + phys*16);
      }
      #pragma unroll
      for (int tj = 0; tj < 4; tj++){
        int row  = n_w + tj*16 + c15;
        int phys = (kw*4 + (lane>>4)) ^ (row&7);
        bf[tj] = *(const f16x8*)(ldsB + row*128 + phys*16);
      }
      #pragma unroll
      for (int ti = 0; ti < 4; ti++)
        #pragma unroll
        for (int tj = 0; tj < 4; tj++)
          acc[ti][tj] = __builtin_amdgcn_mfma_f32_16x16x32_f16(af[ti], bf[tj], acc[ti][tj], 0, 0, 0);
    }
  }
}

// ================= prep kernels (all dst chunk-major) =================

__global__ void k_pack5(const float* W0, const float* W1, const float* W2,
                        const float* W3, const float* W4, char* ws)
{
  f16* dst = (f16*)(ws + OFF_PACKW5);
  const int mat = blockIdx.y;
  const float* src = mat==0?W0 : mat==1?W1 : mat==2?W2 : mat==3?W3 : W4;
  int tid = blockIdx.x*256 + threadIdx.x;       // < 524288
  int n = tid >> 7, kc8 = tid & 127, k = kc8*8;
  int r = ((n&3) << 10) + (n >> 2);
  const float* s = src + (size_t)r*HID + k;
  f16x8 o;
  #pragma unroll
  for (int i = 0; i < 8; i++) o[i] = (f16)s[i];
  *(f16x8*)(dst + (size_t)mat*MSZ + (size_t)(k>>6)*CS_W + (size_t)n*64 + (k&63)) = o;
}

__global__ void k_packwih1(const float* __restrict__ Wih1, char* ws){
  f16* dst = (f16*)(ws + OFF_WIH1);
  int n = blockIdx.x, k = threadIdx.x;
  int r = ((n&3) << 10) + (n >> 2);
  dst[(size_t)(k>>6)*CS_W + (size_t)n*64 + (k&63)] = (k < 227) ? (f16)Wih1[(size_t)r*227 + k] : (f16)0.f;
}

__global__ void k_packwd(const float* __restrict__ Wd, char* ws){
  f16* dst = (f16*)(ws + OFF_WD);     // WD' [16][256][64]
  int o = blockIdx.x;
  #pragma unroll
  for (int j = 0; j < 4; j++){
    int k = threadIdx.x + j*256;
    dst[(size_t)(k>>6)*16384 + (size_t)o*64 + (k&63)] = (o < 227) ? (f16)Wd[(size_t)o*HID + k] : (f16)0.f;
  }
}

__global__ void k_packwdt(const float* __restrict__ Wd, char* ws){
  f16* dst = (f16*)(ws + OFF_H2ALL);  // WdT' [4][1024][64] scratch
  int h = blockIdx.x, o = threadIdx.x;
  dst[(size_t)(o>>6)*65536 + (size_t)h*64 + (o&63)] = (o < 227) ? (f16)Wd[(size_t)o*HID + h] : (f16)0.f;
}

__global__ void k_xpad(const float* __restrict__ seq, char* ws){
  f16* dst = (f16*)(ws + OFF_XPAD);   // [t][4][256][64]
  int idx = blockIdx.x*256 + threadIdx.x;
  int t = idx >> 16, rem = idx & 65535, b = rem >> 8, k = rem & 255;
  f16 v = (k < 227) ? (f16)seq[(size_t)b*22700 + (size_t)t*227 + k] : (f16)0.f;
  dst[(size_t)t*65536 + (size_t)(k>>6)*CS_H + (size_t)b*64 + (k&63)] = v;
}

__global__ void k_bias(const float* bih1, const float* bhh1, const float* bih2, const float* bhh2,
                       const float* bih3, const float* bhh3, const float* Wih1, const float* bd,
                       char* ws)
{
  int n = blockIdx.x*256 + threadIdx.x;
  if (n >= NG) return;
  int r = ((n&3) << 10) + (n >> 2);
  float* b = (float*)(ws + OFF_BIAS);
  float bf = bih1[r] + bhh1[r];
  float s = 0.f;
  for (int o = 0; o < 227; o++) s += Wih1[(size_t)r*227 + o] * bd[o];
  b[n]        = bf;
  b[NG + n]   = bf + s;
  b[2*NG + n] = bih2[r] + bhh2[r];
  b[3*NG + n] = bih3[r] + bhh3[r];
}

// W1D = WIH1' @ WdT' : out rows 4096, cols 1024, K=256; dst chunk-major
__global__ __launch_bounds__(256, 2) void k_w1d(char* ws)
{
  __shared__ __align__(16) char ldsA[16384];
  __shared__ __align__(16) char ldsB[16384];
  const int w = threadIdx.x >> 6, lane = threadIdx.x & 63;
  const int n0 = blockIdx.x*128, m0 = blockIdx.y*128;
  const f16* A  = (const f16*)(ws + OFF_WIH1);
  const f16* Bp = (const f16*)(ws + OFF_H2ALL);
  f16* W1D = (f16*)(ws + OFF_W1D);

  f32x4 acc[4][4];
  f32x4 zero = {0.f, 0.f, 0.f, 0.f};
  #pragma unroll
  for (int i = 0; i < 4; i++)
    #pragma unroll
    for (int j = 0; j < 4; j++) acc[i][j] = zero;

  gemm_tile_cm(acc, A, CS_W, m0, Bp, 65536, n0, KX, ldsA, ldsB, w, lane);

  const int m_w = (w>>1)*64, n_w = (w&1)*64, quad = lane>>4, c15 = lane&15;
  #pragma unroll
  for (int tj = 0; tj < 4; tj++){
    int col = n0 + n_w + tj*16 + c15;
    #pragma unroll
    for (int ti = 0; ti < 4; ti++){
      f32x4 v = acc[ti][tj];
      #pragma unroll
      for (int r = 0; r < 4; r++){
        int m = m0 + m_w + ti*16 + quad*4 + r;
        W1D[(size_t)(col>>6)*CS_W + (size_t)m*64 + (col&63)] = (f16)v[r];
      }
    }
  }
}

// ================= recurrent step kernel =================
// grid (64 ntiles, 3 layers), 256 threads, Tm=256 x Tn=64, BK=64, chunk-major operands.
// Depth-4 register staging of fully-coalesced plain loads (10 x 1KB per wave per chunk),
// LDS 2 x 40KB ping-pong, raw s_barrier + manual lgkmcnt only (no vmcnt drains).
__global__ __launch_bounds__(256, 1) void k_step(char* __restrict__ ws, int t, int use_gt)
{
  __shared__ __align__(16) char lds[81920];
  const int w = threadIdx.x >> 6, lane = threadIdx.x & 63;
  const int col0 = blockIdx.x*64, layer = blockIdx.y;
  const int c15 = lane & 15, quad = lane >> 4;
  const int lr = lane >> 3, lb = lane & 7;

  const f16* packW = (const f16*)(ws + OFF_PACKW5);
  const f16* W1D   = (const f16*)(ws + OFF_W1D);
  const f16* WIH1  = (const f16*)(ws + OFF_WIH1);
  const f16* XP    = (const f16*)(ws + OFF_XPAD) + (size_t)t*65536;
  const float* biasb = (const float*)(ws + OFF_BIAS);
  float* Cst = (float*)(ws + OFF_C);
  f16* HB  = (f16*)(ws + OFF_HBUF);
  f16* H2Z = (f16*)(ws + OFF_H2Z);
  f16* H2A = (f16*)(ws + OFF_H2ALL);

  const int pr = t & 1, pw = pr ^ 1;
  const f16* h0p = HB + (size_t)(pr*2 + 0)*BB*HID;
  const f16* h1p = HB + (size_t)(pr*2 + 1)*BB*HID;
  const f16* h2p; size_t csH2;
  if (t == 0){ h2p = H2Z; csH2 = CS_H; }
  else       { h2p = H2A + (size_t)(t-1)*16384; csH2 = CS_H2; }

  const f16 *A0, *A1, *B0, *B1; size_t csA1; int nc1;
  const float* biasp; f16* hout; size_t houtCS; float* cptr;
  if (layer == 0){
    A0 = h0p; B0 = packW;
    if (use_gt){ A1 = XP;  B1 = WIH1; csA1 = CS_H; nc1 = 4;  biasp = biasb; }
    else       { A1 = h2p; B1 = W1D;  csA1 = csH2; nc1 = 16; biasp = biasb + NG; }
    hout = HB + (size_t)(pw*2 + 0)*BB*HID; houtCS = CS_H; cptr = Cst;
  } else if (layer == 1){
    A0 = h0p; B0 = packW + MSZ;  A1 = h1p; B1 = packW + 2*MSZ; csA1 = CS_H; nc1 = 16;
    biasp = biasb + 2*NG; hout = HB + (size_t)(pw*2 + 1)*BB*HID; houtCS = CS_H;
    cptr = Cst + (size_t)BB*HID;
  } else {
    A0 = h1p; B0 = packW + 3*MSZ; A1 = h2p; B1 = packW + 4*MSZ; csA1 = csH2; nc1 = 16;
    biasp = biasb + 3*NG; hout = H2A + (size_t)t*16384; houtCS = CS_H2;
    cptr = Cst + (size_t)2*BB*HID;
  }
  const int ncmax = 16 + nc1;                  // 32 or 20 (both multiples of 4)

  // coalesced per-lane offsets (elements); q adds 512 (8 rows x 64)
  const int offA = w*4096 + lr*64 + lb*8;
  const int offB = (col0 + w*16 + lr)*64 + lb*8;
  // LDS write offsets (bytes, within buffer); q adds 1024; XOR swizzle on LDS side
  const int wA = w*8192 + lr*128 + ((lb ^ lr) << 4);
  const int wB = 32768 + (w*16 + lr)*128 + ((lb ^ lr) << 4);

  f16x8 stA[4][8], stB[4][2];
  f32x4 acc[4][4];
  f32x4 zero = {0.f, 0.f, 0.f, 0.f};
  #pragma unroll
  for (int i = 0; i < 4; i++)
    #pragma unroll
    for (int j = 0; j < 4; j++) acc[i][j] = zero;

  const int m_w = w*64;
  const int p0 = (quad ^ (c15&7)) * 16;
  const int p1 = ((4 + quad) ^ (c15&7)) * 16;
  int rA[4], rB[4];
  #pragma unroll
  for (int ti = 0; ti < 4; ti++) rA[ti] = (m_w + ti*16 + c15) * 128;
  #pragma unroll
  for (int tj = 0; tj < 4; tj++) rB[tj] = 32768 + (tj*16 + c15) * 128;

#define LD(cv, st) { const int c_ = (cv); const f16 *pa_, *pb_;                                  \
  if (c_ < 16){ pa_ = A0 + (size_t)c_*CS_H;        pb_ = B0 + (size_t)c_*CS_W; }                 \
  else        { pa_ = A1 + (size_t)(c_-16)*csA1;   pb_ = B1 + (size_t)(c_-16)*CS_W; }            \
  _Pragma("unroll") for (int q_ = 0; q_ < 8; q_++) stA[st][q_] = *(const f16x8*)(pa_ + offA + q_*512); \
  _Pragma("unroll") for (int q_ = 0; q_ < 2; q_++) stB[st][q_] = *(const f16x8*)(pb_ + offB + q_*512); }

#define WR(st, bf_) { char* la_ = lds + (bf_)*40960;                                             \
  _Pragma("unroll") for (int q_ = 0; q_ < 8; q_++) *(f16x8*)(la_ + wA + q_*1024) = stA[st][q_];  \
  _Pragma("unroll") for (int q_ = 0; q_ < 2; q_++) *(f16x8*)(la_ + wB + q_*1024) = stB[st][q_]; }

#define CM(bf_) { const char* lc_ = lds + (bf_)*40960;                                           \
  f16x8 af_[4], bfr_[4];                                                                         \
  _Pragma("unroll") for (int ti_ = 0; ti_ < 4; ti_++) af_[ti_]  = *(const f16x8*)(lc_ + rA[ti_] + p0); \
  _Pragma("unroll") for (int tj_ = 0; tj_ < 4; tj_++) bfr_[tj_] = *(const f16x8*)(lc_ + rB[tj_] + p0); \
  _Pragma("unroll") for (int ti_ = 0; ti_ < 4; ti_++)                                            \
    _Pragma("unroll") for (int tj_ = 0; tj_ < 4; tj_++)                                          \
      acc[ti_][tj_] = __builtin_amdgcn_mfma_f32_16x16x32_f16(af_[ti_], bfr_[tj_], acc[ti_][tj_], 0, 0, 0); \
  _Pragma("unroll") for (int ti_ = 0; ti_ < 4; ti_++) af_[ti_]  = *(const f16x8*)(lc_ + rA[ti_] + p1); \
  _Pragma("unroll") for (int tj_ = 0; tj_ < 4; tj_++) bfr_[tj_] = *(const f16x8*)(lc_ + rB[tj_] + p1); \
  _Pragma("unroll") for (int ti_ = 0; ti_ < 4; ti_++)                                            \
    _Pragma("unroll") for (int tj_ = 0; tj_ < 4; tj_++)                                          \
      acc[ti_][tj_] = __builtin_amdgcn_mfma_f32_16x16x32_f16(af_[ti_], bfr_[tj_], acc[ti_][tj_], 0, 0, 0); }

#define FENCE_BAR asm volatile("s_waitcnt lgkmcnt(0)" ::: "memory"); __builtin_amdgcn_s_barrier();

#define STEP(cv, i) {                                                                            \
  const int c_s = (cv);                                                                          \
  if (c_s + 1 < ncmax) WR(((i)+1)&3, ((i)+1)&1);   /* stage chunk c+1 into other LDS buf */      \
  if (c_s + 4 < ncmax) LD(c_s + 4, (i));           /* refill freed register stage */             \
  CM((i)&1);                                        /* consume chunk c from LDS */               \
  FENCE_BAR }

  LD(0, 0); LD(1, 1); LD(2, 2); LD(3, 3);
  WR(0, 0);
  FENCE_BAR
  for (int cc = 0; cc < ncmax; cc += 4){
    STEP(cc + 0, 0);
    STEP(cc + 1, 1);
    STEP(cc + 2, 2);
    STEP(cc + 3, 3);
  }
#undef LD
#undef WR
#undef CM
#undef FENCE_BAR
#undef STEP

  // ---- fused LSTM cell epilogue ----
  const int gl = lane & 3, sbase = lane & 60;
  #pragma unroll
  for (int tj = 0; tj < 4; tj++){
    const int ncol = col0 + tj*16 + c15;
    const int unit = ncol >> 2;
    const float bn = biasp[ncol];
    float cp[16];
    #pragma unroll
    for (int ti = 0; ti < 4; ti++)
      #pragma unroll
      for (int r = 0; r < 4; r++)
        cp[ti*4 + r] = cptr[(size_t)(m_w + ti*16 + quad*4 + r)*HID + unit];
    #pragma unroll
    for (int ti = 0; ti < 4; ti++){
      f32x4 v = acc[ti][tj];
      #pragma unroll
      for (int r = 0; r < 4; r++){
        float x   = v[r] + bn;
        float act = (gl == 2) ? tanh_fast(x) : sigf(x);
        float iv = __shfl(act, sbase);
        float fv = __shfl(act, sbase + 1);
        float gv = __shfl(act, sbase + 2);
        float ov = __shfl(act, sbase + 3);
        float cn = fmaf(fv, cp[ti*4 + r], iv*gv);
        float hn = ov * tanh_fast(cn);
        int m = m_w + ti*16 + quad*4 + r;
        if (gl == 0)      cptr[(size_t)m*HID + unit] = cn;
        else if (gl == 1) hout[(size_t)(unit>>6)*houtCS + (size_t)m*64 + (unit&63)] = (f16)hn;
      }
    }
  }
}

// ================= final output GEMM =================
__global__ __launch_bounds__(256, 2) void k_final(const char* __restrict__ ws,
                                                  const float* __restrict__ bd,
                                                  float* __restrict__ dout)
{
  __shared__ __align__(16) char ldsA[16384];
  __shared__ __align__(16) char ldsB[16384];
  const int w = threadIdx.x >> 6, lane = threadIdx.x & 63;
  const int n0 = blockIdx.x*128, m0 = blockIdx.y*128;
  const f16* A  = (const f16*)(ws + OFF_H2ALL);   // chunk-major, cs = CS_H2
  const f16* Bp = (const f16*)(ws + OFF_WD);      // WD' [16][256][64]

  f32x4 acc[4][4];
  f32x4 zero = {0.f, 0.f, 0.f, 0.f};
  #pragma unroll
  for (int i = 0; i < 4; i++)
    #pragma unroll
    for (int j = 0; j < 4; j++) acc[i][j] = zero;

  gemm_tile_cm(acc, A, CS_H2, m0, Bp, 16384, n0, HID, ldsA, ldsB, w, lane);

  const int m_w = (w>>1)*64, n_w = (w&1)*64, quad = lane>>4, c15 = lane&15;
  #pragma unroll
  for (int tj = 0; tj < 4; tj++){
    int o = n0 + n_w + tj*16 + c15;
    bool valid = (o < 227);
    float bn = valid ? bd[o] : 0.f;
    #pragma unroll
    for (int ti = 0; ti < 4; ti++){
      f32x4 v = acc[ti][tj];
      #pragma unroll
      for (int r = 0; r < 4; r++){
        int m = m0 + m_w + ti*16 + quad*4 + r;
        if (valid){
          int tt = m >> 8, b = m & 255;
          dout[(size_t)b*22700 + (size_t)tt*227 + o] = v[r] + bn;
        }
      }
    }
  }
}

// ================= host =================
extern "C" void kernel_launch(void* const* d_in, const int* in_sizes, int n_in,
                              void* d_out, int out_size, void* d_ws, size_t ws_size,
                              hipStream_t stream)
{
  (void)in_sizes; (void)n_in; (void)out_size; (void)ws_size;
  const float* seq  = (const float*)d_in[0];
  const float* Wih1 = (const float*)d_in[1];
  const float* Whh1 = (const float*)d_in[2];
  const float* bih1 = (const float*)d_in[3];
  const float* bhh1 = (const float*)d_in[4];
  const float* Wih2 = (const float*)d_in[5];
  const float* Whh2 = (const float*)d_in[6];
  const float* bih2 = (const float*)d_in[7];
  const float* bhh2 = (const float*)d_in[8];
  const float* Wih3 = (const float*)d_in[9];
  const float* Whh3 = (const float*)d_in[10];
  const float* bih3 = (const float*)d_in[11];
  const float* bhh3 = (const float*)d_in[12];
  const float* Wd   = (const float*)d_in[13];
  const float* bd   = (const float*)d_in[14];
  char* ws = (char*)d_ws;

  hipMemsetAsync(ws + OFF_C,    0, (size_t)3*BB*HID*4, stream);
  hipMemsetAsync(ws + OFF_HBUF, 0, (size_t)2*BB*HID*2, stream);
  hipMemsetAsync(ws + OFF_H2Z,  0, (size_t)BB*HID*2,   stream);

  k_pack5   <<<dim3(2048, 5), dim3(256), 0, stream>>>(Whh1, Wih2, Whh2, Wih3, Whh3, ws);
  k_packwih1<<<dim3(4096),    dim3(256), 0, stream>>>(Wih1, ws);
  k_packwd  <<<dim3(256),     dim3(256), 0, stream>>>(Wd, ws);
  k_packwdt <<<dim3(1024),    dim3(256), 0, stream>>>(Wd, ws);
  k_xpad    <<<dim3(25600),   dim3(256), 0, stream>>>(seq, ws);
  k_bias    <<<dim3(16),      dim3(256), 0, stream>>>(bih1, bhh1, bih2, bhh2, bih3, bhh3, Wih1, bd, ws);
  k_w1d     <<<dim3(8, 32),   dim3(256), 0, stream>>>(ws);

  for (int t = 0; t < TT; t++){
    int ug = ((t % 10) < 5) ? 1 : 0;
    k_step<<<dim3(64, 3), dim3(256), 0, stream>>>(ws, t, ug);
  }

  k_final<<<dim3(2, 200), dim3(256), 0, stream>>>((const char*)ws, bd, (float*)d_out);
}